// Round 5
// baseline (1818.792 us; speedup 1.0000x reference)
//
#include <hip/hip_runtime.h>
#include <hip/hip_bf16.h>
#include <stdint.h>

typedef __hip_bfloat16 bf16;
typedef unsigned long long u64;
typedef unsigned int u32;
typedef short short8 __attribute__((ext_vector_type(8)));
typedef float f32x4 __attribute__((ext_vector_type(4)));

#define D_ 128   // memory dim
// fallback tile (round-0 proven kernel, reads weights directly)
#define BM 64
#define BN 128
#define BK 64
#define KFB 640

__device__ __forceinline__ float bf2f(bf16 v) { return __bfloat162float(v); }
__device__ __forceinline__ u32 fbits(float f) { union { float f; u32 u; } c; c.f = f; return c.u; }
__device__ __forceinline__ u32 pk2(float a, float b) {
  union { bf16 h; unsigned short s; } x, y;
  x.h = __float2bfloat16(a); y.h = __float2bfloat16(b);
  return (u32)x.s | ((u32)y.s << 16);
}
union U4S8 { uint4 u; short8 s; };
__device__ __forceinline__ short8 u2s(uint4 v) { U4S8 c; c.u = v; return c.s; }
template<bool F32>
__device__ __forceinline__ float ldE(const void* p, size_t i) {
  return F32 ? ((const float*)p)[i] : bf2f(((const bf16*)p)[i]);
}
template<bool F32>
__device__ __forceinline__ void stE(void* p, size_t i, float v) {
  if (F32) ((float*)p)[i] = v; else ((bf16*)p)[i] = __float2bfloat16(v);
}
template<bool F32>
__device__ __forceinline__ uint4 ld8(const void* base, size_t elemOff) {
  if (!F32) {
    return *(const uint4*)((const bf16*)base + elemOff);
  } else {
    const float4* p = (const float4*)((const float*)base + elemOff);
    float4 v0 = p[0], v1 = p[1];
    uint4 o; o.x = pk2(v0.x, v0.y); o.y = pk2(v0.z, v0.w);
    o.z = pk2(v1.x, v1.y); o.w = pk2(v1.z, v1.w);
    return o;
  }
}
template<bool F32>
__device__ __forceinline__ void stage8(const void* base, size_t elemOff, bf16* dst) {
  *(uint4*)dst = ld8<F32>(base, elemOff);
}

// ---- prep: zero scatter keys + cnt, sniff dtype (0 = bf16, 1 = fp32) ------
__global__ void k_prep(u64* __restrict__ key, u32* __restrict__ cnt, int N,
                       const u32* __restrict__ mem_w, const u32* __restrict__ t_w,
                       u32* __restrict__ flag) {
  int i = blockIdx.x * blockDim.x + threadIdx.x;
  if (i < N) key[i] = 0ull;
  if (i == 0) {
    *cnt = 0u;
    int ok = 1;
    for (int k = 0; k < 64; ++k) {
      u32 w = mem_w[k];
      if ((w & 0x7fffu) > 0x4300u) ok = 0;
      if (((w >> 16) & 0x7fffu) > 0x4300u) ok = 0;
    }
    for (int k = 0; k < 16; ++k) {
      u32 w = t_w[k];
      if ((w & 0xffffu) > 0x4480u) ok = 0;
      if ((w >> 16) > 0x4480u) ok = 0;
    }
    *flag = ok ? 0u : 1u;
  }
}

// ---- single scatter pass: per-node lexicographic max of (t_bits, pos+1) ---
__global__ void k_scat(const int* __restrict__ src, const int* __restrict__ dst,
                       const void* __restrict__ t, const u32* __restrict__ flag,
                       u64* __restrict__ key, int E) {
  int i = blockIdx.x * blockDim.x + threadIdx.x;
  if (i >= 2 * E) return;
  int e = (i < E) ? i : i - E;
  int node = (i < E) ? src[e] : dst[e];
  float tv = (*flag) ? ((const float*)t)[e] : bf2f(((const bf16*)t)[e]);
  u64 k = ((u64)fbits(tv) << 32) | (u64)(u32)(i + 1);  // t >= 0: bit order == value order
  atomicMax(&key[node], k);
}

// ---- pack folded weights W'' (K=512), frag-linear for direct B-frag loads.
// W''[j][k] for a tile (kc,by): j in [0,128): grp=j>>5 (w), gi=j&31, gidx=32*by+gi.
//   grp0 (r):  wih[gidx][k]      + (k<128 ? whh[gidx][k] : 0)
//   grp1 (z):  wih[128+gidx][k]  + (k<128 ? whh[128+gidx][k] : 0)
//   grp2 (in): wih[256+gidx][k]
//   grp3 (hn): k<128 ? whh[256+gidx][k] : 0
// Layout: group g = ((tile*16 + (w*4+ks2*2+ni))*64 + lane), 16B per group;
// lane: mrow=lane&15, quad=lane>>4; element k = kc*64 + ks2*32 + quad*8 + q.
__global__ void k_pack3(const void* __restrict__ wih, const void* __restrict__ whh,
                        const u32* __restrict__ flag, bf16* __restrict__ wpk) {
  int g = blockIdx.x * 256 + threadIdx.x;
  if (g >= 32768) return;                  // 32 tiles x 16 subs x 64 lanes
  int tile = g >> 10, sub = (g >> 6) & 15, lane = g & 63;
  int w = sub >> 2, ks2 = (sub >> 1) & 1, ni = sub & 1;
  int mrow = lane & 15, quad = lane >> 4;
  int j = 32 * w + 16 * ni + mrow;
  int kk = ks2 * 32 + quad * 8;
  int kc = tile >> 2, by = tile & 3;
  int kglob = kc * 64 + kk;
  int grp = j >> 5, gi = j & 31, gidx = 32 * by + gi;
  bool F = (*flag != 0);
  float f[8];
#pragma unroll
  for (int q = 0; q < 8; ++q) {
    int k = kglob + q;
    float v = 0.f;
    if (grp < 3) {
      int srow = grp * 128 + gidx;
      v = F ? ldE<true>(wih, (size_t)srow * 512 + k) : ldE<false>(wih, (size_t)srow * 512 + k);
      if (k < 128 && grp < 2)
        v += F ? ldE<true>(whh, (size_t)srow * 128 + k) : ldE<false>(whh, (size_t)srow * 128 + k);
    } else if (k < 128) {
      v = F ? ldE<true>(whh, (size_t)(256 + gidx) * 128 + k)
            : ldE<false>(whh, (size_t)(256 + gidx) * 128 + k);
    }
    f[q] = v;
  }
  uint4 o; o.x = pk2(f[0], f[1]); o.y = pk2(f[2], f[3]);
  o.z = pk2(f[4], f[5]); o.w = pk2(f[6], f[7]);
  ((uint4*)wpk)[g] = o;
}

// ---- compact: passthrough inactive rows, out_last for all, optional list.
template<bool F32>
__device__ __forceinline__ void compact_body(int n, bool nvalid,
                                             const void* mem, const void* lastup,
                                             const void* t, const u64* key,
                                             int* list, u32* cnt, int use_list,
                                             void* out, int N, int E, u32* s_wb) {
  u32 b = 0;
  if (nvalid) b = (u32)key[n];
  bool active = nvalid && (b != 0u);
  if (use_list) {
    u64 mask = __ballot(active);
    int lane = threadIdx.x & 63, w = threadIdx.x >> 6;
    if (lane == 0) s_wb[w] = (u32)__popcll(mask);
    __syncthreads();
    if (threadIdx.x == 0) {
      u32 tot = s_wb[0] + s_wb[1] + s_wb[2] + s_wb[3];
      u32 base = tot ? atomicAdd(cnt, tot) : 0u;
      u32 acc0 = base;
      for (int i = 0; i < 4; ++i) { u32 c = s_wb[i]; s_wb[i] = acc0; acc0 += c; }
    }
    __syncthreads();
    if (active) {
      u32 idx = s_wb[w] + (u32)__popcll(mask & ((1ull << lane) - 1ull));
      list[idx] = n;
    }
  }
  if (!nvalid) return;
  if (active) {
    int pos = (int)(b - 1u);
    int e = (pos < E) ? pos : pos - E;
    stE<F32>(out, (size_t)N * D_ + n, ldE<F32>(t, e));
  } else {
    if (F32) {
      const float4* s = (const float4*)((const float*)mem + (size_t)n * D_);
      float4* d = (float4*)((float*)out + (size_t)n * D_);
#pragma unroll
      for (int i = 0; i < 32; ++i) d[i] = s[i];
    } else {
      const uint4* s = (const uint4*)((const bf16*)mem + (size_t)n * D_);
      uint4* d = (uint4*)((bf16*)out + (size_t)n * D_);
#pragma unroll
      for (int i = 0; i < 16; ++i) d[i] = s[i];
    }
    stE<F32>(out, (size_t)N * D_ + n, ldE<F32>(lastup, n));
  }
}
__global__ void k_compact(const void* mem, const void* lastup, const void* t,
                          const u32* __restrict__ flag, const u64* __restrict__ key,
                          int* list, u32* cnt, int use_list,
                          void* out, int N, int E) {
  __shared__ u32 s_wb[4];
  int n = blockIdx.x * blockDim.x + threadIdx.x;
  bool nvalid = (n < N);
  if (*flag) compact_body<true>(n, nvalid, mem, lastup, t, key, list, cnt, use_list, out, N, E, s_wb);
  else       compact_body<false>(n, nvalid, mem, lastup, t, key, list, cnt, use_list, out, N, E, s_wb);
}

// ============================================================================
// k_gemm3: barrier-free fused GEMM+GRU. BM=32 rows, K=512 (folded), 8 kc x 4 by
// = 32 phases, fully unrolled. A and B fragments loaded global->VGPR directly
// (no LDS staging, no K-loop barriers). B: rotating 3 reg-sets, depth-2
// prefetch from frag-linear wpk3 (L2-resident, 1KB coalesced per instr).
// A: bf16 = ping-pong prefetch one kc ahead; f32 = inline load+cvt at by0.
// Wave 3 (h_n group) has zero B for kc>=2 -> skips those loads & MFMAs.
// ============================================================================
template<bool F32>
__device__ __forceinline__ void gemm3_body(
    const void* mem, const void* lastup, const void* t, const void* feat,
    const int* __restrict__ src, const int* __restrict__ dst,
    const bf16* __restrict__ wpk,
    const void* bih, const void* bhh, const void* tw, const void* tb,
    const u64* __restrict__ key, const int* __restrict__ list,
    const u32* __restrict__ cnt, int use_list,
    void* out, int N, int E,
    float (*Gs)[132], int* s_node, int* s_e, int* s_oth, int* s_act,
    float* s_dt, float* s_twb) {
  const int tid = threadIdx.x;
  const int bx = blockIdx.x;

  if (tid < 32) {
    int r = tid, row = 32 * bx + r, node = -1;
    if (use_list) { int c = (int)*cnt; if (row < c) node = list[row]; }
    else if (row < N) node = row;
    int act = 0, e = 0, oth = 0; float dtv = 0.f;
    if (node >= 0) {
      u32 b = (u32)key[node];
      if (b) {
        act = 1;
        int pos = (int)(b - 1u);
        if (pos < E) { e = pos; oth = dst[e]; } else { e = pos - E; oth = src[e]; }
        dtv = ldE<F32>(t, e) - ldE<F32>(lastup, node);
      }
    }
    if (node < 0) node = 0;
    s_node[r] = node; s_e[r] = e; s_oth[r] = oth; s_act[r] = act; s_dt[r] = dtv;
  }
  if (tid >= 128) {
    int i = tid - 128;
    s_twb[i] = ldE<F32>(tw, i);
    s_twb[128 + i] = ldE<F32>(tb, i);
  }
  __syncthreads();   // the ONLY pre-epilogue barrier

  const int w = tid >> 6, l = tid & 63;
  const int mrow = l & 15, quad = l >> 4;
  const bool w3 = (w == 3);
  const int koq = quad * 8;

  // per-lane meta in regs (rows mrow and 16+mrow)
  const int nd0 = s_node[mrow],    nd1 = s_node[16 + mrow];
  const int ot0 = s_oth[mrow],     ot1 = s_oth[16 + mrow];
  const int ev0 = s_e[mrow],       ev1 = s_e[16 + mrow];
  const float dt0 = s_dt[mrow],    dt1 = s_dt[16 + mrow];

  uint4 braw[3][4];     // rotating B frag sets [phase%3][ks2*2+ni]
  uint4 alo[2][4];      // A frag ping-pong [kc&1][ks2*2+mi] (bf16-packed)
  f32x4 acc[4][2][2];
#pragma unroll
  for (int by = 0; by < 4; ++by)
#pragma unroll
    for (int mi = 0; mi < 2; ++mi)
#pragma unroll
      for (int ni = 0; ni < 2; ++ni) acc[by][mi][ni] = (f32x4){0.f, 0.f, 0.f, 0.f};

  auto BISSUE = [&](int tile_) {
    const uint4* bp = (const uint4*)wpk + ((size_t)(tile_ * 16 + w * 4)) * 64 + l;
#pragma unroll
    for (int f = 0; f < 4; ++f) braw[tile_ % 3][f] = bp[(size_t)f * 64];
  };
  auto AROW = [&](int kn, int mi) -> int {
    return (kn < 2) ? (mi ? nd1 : nd0) : (kn < 4) ? (mi ? ot1 : ot0) : (mi ? ev1 : ev0);
  };
  auto ALOADB = [&](int kn) {  // bf16 direct prefetch into alo[kn&1]
#pragma unroll
    for (int ks2 = 0; ks2 < 2; ++ks2)
#pragma unroll
      for (int mi = 0; mi < 2; ++mi) {
        const void* base = (kn < 4) ? mem : feat;
        size_t eo = (size_t)AROW(kn, mi) * D_ + (kn & 1) * 64 + ks2 * 32 + koq;
        alo[kn & 1][ks2 * 2 + mi] = *(const uint4*)((const bf16*)base + eo);
      }
  };
  auto ALOADF = [&](int kn) {  // f32 load + cvt inline into alo[kn&1]
#pragma unroll
    for (int ks2 = 0; ks2 < 2; ++ks2)
#pragma unroll
      for (int mi = 0; mi < 2; ++mi) {
        const void* base = (kn < 4) ? mem : feat;
        size_t eo = (size_t)AROW(kn, mi) * D_ + (kn & 1) * 64 + ks2 * 32 + koq;
        const float4* p = (const float4*)((const float*)base + eo);
        float4 v0 = p[0], v1 = p[1];
        uint4 o; o.x = pk2(v0.x, v0.y); o.y = pk2(v0.z, v0.w);
        o.z = pk2(v1.x, v1.y); o.w = pk2(v1.z, v1.w);
        alo[kn & 1][ks2 * 2 + mi] = o;
      }
  };
  auto ACOS = [&](int kc_) {   // time-encoding kc (4,5): pure VALU
#pragma unroll
    for (int ks2 = 0; ks2 < 2; ++ks2) {
      int kbase = (kc_ - 4) * 64 + ks2 * 32 + koq;
      float tv[8], bv[8];
#pragma unroll
      for (int e2 = 0; e2 < 8; ++e2) { tv[e2] = s_twb[kbase + e2]; bv[e2] = s_twb[128 + kbase + e2]; }
#pragma unroll
      for (int mi = 0; mi < 2; ++mi) {
        float dtv = mi ? dt1 : dt0;
        u32 p[4];
#pragma unroll
        for (int e2 = 0; e2 < 4; ++e2)
          p[e2] = pk2(cosf(fmaf(dtv, tv[2 * e2], bv[2 * e2])),
                      cosf(fmaf(dtv, tv[2 * e2 + 1], bv[2 * e2 + 1])));
        alo[kc_ & 1][ks2 * 2 + mi] = (uint4){p[0], p[1], p[2], p[3]};
      }
    }
  };

  // ---- prologue: B(0), A(0), B(1) ----
  BISSUE(0);
  if (F32) ; else ALOADB(0);
  BISSUE(1);

  // ---- 32 phases, fully unrolled, zero barriers ----
#pragma unroll
  for (int kc = 0; kc < 8; ++kc) {
#pragma unroll
    for (int by = 0; by < 4; ++by) {
      const int tt = kc * 4 + by;
      if (tt + 2 < 32 && !(w3 && (tt + 2) >= 8)) BISSUE(tt + 2);
      if (by == 0) {
        if (!(w3 && kc >= 2)) {
          if (kc == 4 || kc == 5) ACOS(kc);
          else if (F32) ALOADF(kc);
        }
        if (!F32) {
          const int kn = kc + 1;
          if ((kn == 1 || kn == 2 || kn == 3 || kn == 6 || kn == 7) && !(w3 && kn >= 2))
            ALOADB(kn);
        }
      }
      if (!(w3 && kc >= 2)) {
        __builtin_amdgcn_s_setprio(1);
#pragma unroll
        for (int ks2 = 0; ks2 < 2; ++ks2)
#pragma unroll
          for (int mi = 0; mi < 2; ++mi)
#pragma unroll
            for (int ni = 0; ni < 2; ++ni)
              acc[by][mi][ni] = __builtin_amdgcn_mfma_f32_16x16x32_bf16(
                  u2s(alo[kc & 1][ks2 * 2 + mi]), u2s(braw[tt % 3][ks2 * 2 + ni]),
                  acc[by][mi][ni], 0, 0, 0);
        __builtin_amdgcn_s_setprio(0);
      }
    }
  }

  // ---- GRU epilogue per by ----
#pragma unroll
  for (int by = 0; by < 4; ++by) {
#pragma unroll
    for (int mi = 0; mi < 2; ++mi)
#pragma unroll
      for (int ni = 0; ni < 2; ++ni)
#pragma unroll
        for (int reg = 0; reg < 4; ++reg)
          Gs[16 * mi + quad * 4 + reg][32 * w + 16 * ni + mrow] = acc[by][mi][ni][reg];
    __syncthreads();
    {
      int r = tid >> 3, giB = (tid & 7) * 4;
      if (s_act[r]) {
        int node = s_node[r];
#pragma unroll
        for (int q = 0; q < 4; ++q) {
          int gi = giB + q, gidx = 32 * by + gi;
          float rp  = Gs[r][gi]      + ldE<F32>(bih, gidx)       + ldE<F32>(bhh, gidx);
          float zp  = Gs[r][32 + gi] + ldE<F32>(bih, 128 + gidx) + ldE<F32>(bhh, 128 + gidx);
          float inp = Gs[r][64 + gi] + ldE<F32>(bih, 256 + gidx);
          float hnp = Gs[r][96 + gi] + ldE<F32>(bhh, 256 + gidx);
          float rg = 1.f / (1.f + expf(-rp));
          float zg = 1.f / (1.f + expf(-zp));
          float ng = tanhf(inp + rg * hnp);
          float h = ldE<F32>(mem, (size_t)node * D_ + gidx);
          stE<F32>(out, (size_t)node * D_ + gidx, (1.f - zg) * ng + zg * h);
        }
      }
    }
    __syncthreads();
  }
}

__global__ __launch_bounds__(256, 3)
void k_gemm3(const void* mem, const void* lastup, const void* t, const void* feat,
             const int* src, const int* dst, const bf16* wpk,
             const void* bih, const void* bhh, const void* tw, const void* tb,
             const u32* __restrict__ flag, const u64* __restrict__ key,
             const int* __restrict__ list, const u32* __restrict__ cnt, int use_list,
             void* out, int N, int E) {
  if (use_list && (int)*cnt <= 32 * (int)blockIdx.x) return;  // uniform, pre-barrier
  __shared__ float Gs[32][132];
  __shared__ int s_node[32], s_e[32], s_oth[32], s_act[32];
  __shared__ float s_dt[32], s_twb[256];
  if (*flag)
    gemm3_body<true>(mem, lastup, t, feat, src, dst, wpk, bih, bhh, tw, tb,
                     key, list, cnt, use_list, out, N, E,
                     Gs, s_node, s_e, s_oth, s_act, s_dt, s_twb);
  else
    gemm3_body<false>(mem, lastup, t, feat, src, dst, wpk, bih, bhh, tw, tb,
                      key, list, cnt, use_list, out, N, E,
                      Gs, s_node, s_e, s_oth, s_act, s_dt, s_twb);
}

// ============================================================================
// FALLBACK (tiny ws): round-0 proven kernel, grid (mtiles,4), reads raw weights.
// ============================================================================
template<bool F32>
__device__ __forceinline__ void gemm_body(
    const void* mem, const void* lastup, const void* t, const void* feat,
    const int* __restrict__ src, const int* __restrict__ dst,
    const void* wih, const void* whh, const void* bih, const void* bhh,
    const void* tw, const void* tb,
    const u64* __restrict__ key, const int* __restrict__ list,
    const u32* __restrict__ cnt, int use_list,
    void* out, int N, int E,
    bf16 (*As)[72], bf16 (*Bs)[72], float (*Gs)[132],
    int* s_node, int* s_e, int* s_oth, int* s_act, float* s_dt) {
  const int tid = threadIdx.x;
  const int bx = blockIdx.x, by = blockIdx.y;

  if (tid < BM) {
    int r = tid;
    int row = BM * bx + r;
    int node = -1;
    if (use_list) { int c = (int)*cnt; if (row < c) node = list[row]; }
    else if (row < N) node = row;
    int act = 0, e = 0, oth = 0; float dtv = 0.f;
    if (node >= 0) {
      u32 b = (u32)key[node];
      if (b) {
        act = 1;
        int pos = (int)(b - 1u);
        if (pos < E) { e = pos; oth = dst[e]; } else { e = pos - E; oth = src[e]; }
        dtv = ldE<F32>(t, e) - ldE<F32>(lastup, node);
      }
    }
    if (node < 0) node = 0;
    s_node[r] = node; s_e[r] = e; s_oth[r] = oth; s_act[r] = act; s_dt[r] = dtv;
  }

  const int w = tid >> 6, l = tid & 63;
  const int mrow = l & 15, quad = l >> 4;
  f32x4 acc[4][2];
#pragma unroll
  for (int mi = 0; mi < 4; ++mi)
#pragma unroll
    for (int ni = 0; ni < 2; ++ni) acc[mi][ni] = (f32x4){0.f, 0.f, 0.f, 0.f};

#pragma unroll 1
  for (int kc = 0; kc < KFB / BK; ++kc) {
    __syncthreads();
#pragma unroll
    for (int it = 0; it < 2; ++it) {
      int task = tid + 256 * it;
      int r = task >> 3, s = task & 7;
      int k0 = kc * BK + s * 8;
      bf16* dstp = &As[r][s * 8];
      if (k0 < 128)       stage8<F32>(mem,  (size_t)s_node[r] * D_ + k0, dstp);
      else if (k0 < 256)  stage8<F32>(mem,  (size_t)s_oth[r] * D_ + (k0 - 128), dstp);
      else if (k0 < 384) {
        float dtv = s_dt[r];
        float f[8];
#pragma unroll
        for (int q = 0; q < 8; ++q) {
          int j = k0 - 256 + q;
          f[q] = cosf(fmaf(dtv, ldE<F32>(tw, j), ldE<F32>(tb, j)));
        }
        uint4 o; o.x = pk2(f[0], f[1]); o.y = pk2(f[2], f[3]);
        o.z = pk2(f[4], f[5]); o.w = pk2(f[6], f[7]);
        *(uint4*)dstp = o;
      }
      else if (k0 < 512)  stage8<F32>(feat, (size_t)s_e[r] * D_ + (k0 - 384), dstp);
      else                stage8<F32>(mem,  (size_t)s_node[r] * D_ + (k0 - 512), dstp);
    }
#pragma unroll
    for (int it = 0; it < 4; ++it) {
      int task = tid + 256 * it;
      int j = task >> 3, s = task & 7;
      int k0 = kc * BK + s * 8;
      int grp = j >> 5, gi = j & 31;
      int gidx = 32 * by + gi;
      bf16* dstp = &Bs[j][s * 8];
      if (k0 < 512) {
        if (grp == 3) { *(uint4*)dstp = (uint4){0, 0, 0, 0}; }
        else {
          int srow = (grp == 0) ? gidx : (grp == 1) ? 128 + gidx : 256 + gidx;
          stage8<F32>(wih, (size_t)srow * 512 + k0, dstp);
        }
      } else {
        if (grp == 2) { *(uint4*)dstp = (uint4){0, 0, 0, 0}; }
        else {
          int srow = (grp == 0) ? gidx : (grp == 1) ? 128 + gidx : 256 + gidx;
          stage8<F32>(whh, (size_t)srow * D_ + (k0 - 512), dstp);
        }
      }
    }
    __syncthreads();
#pragma unroll
    for (int ks = 0; ks < BK; ks += 32) {
      short8 a[4], b[2];
#pragma unroll
      for (int mi = 0; mi < 4; ++mi)
        a[mi] = *(const short8*)&As[16 * mi + mrow][ks + quad * 8];
#pragma unroll
      for (int ni = 0; ni < 2; ++ni)
        b[ni] = *(const short8*)&Bs[32 * w + 16 * ni + mrow][ks + quad * 8];
#pragma unroll
      for (int mi = 0; mi < 4; ++mi)
#pragma unroll
        for (int ni = 0; ni < 2; ++ni)
          acc[mi][ni] = __builtin_amdgcn_mfma_f32_16x16x32_bf16(a[mi], b[ni], acc[mi][ni], 0, 0, 0);
    }
  }

#pragma unroll
  for (int mi = 0; mi < 4; ++mi)
#pragma unroll
    for (int ni = 0; ni < 2; ++ni)
#pragma unroll
      for (int reg = 0; reg < 4; ++reg)
        Gs[16 * mi + quad * 4 + reg][32 * w + 16 * ni + mrow] = acc[mi][ni][reg];
  __syncthreads();

  {
    int r = tid >> 2;
    int giB = (tid & 3) * 8;
    if (s_act[r]) {
      int node = s_node[r];
#pragma unroll
      for (int q = 0; q < 8; ++q) {
        int gi = giB + q;
        int gidx = 32 * by + gi;
        float rp  = Gs[r][gi]       + ldE<F32>(bih, gidx)       + ldE<F32>(bhh, gidx);
        float zp  = Gs[r][32 + gi]  + ldE<F32>(bih, 128 + gidx) + ldE<F32>(bhh, 128 + gidx);
        float inp = Gs[r][64 + gi]  + ldE<F32>(bih, 256 + gidx);
        float hnp = Gs[r][96 + gi]  + ldE<F32>(bhh, 256 + gidx);
        float rg = 1.f / (1.f + expf(-rp));
        float zg = 1.f / (1.f + expf(-zp));
        float ng = tanhf(inp + rg * hnp);
        float h = ldE<F32>(mem, (size_t)node * D_ + gidx);
        stE<F32>(out, (size_t)node * D_ + gidx, (1.f - zg) * ng + zg * h);
      }
    }
  }
}

__global__ __launch_bounds__(256)
void k_gemm_fb(const void* mem, const void* lastup, const void* t, const void* feat,
               const int* src, const int* dst,
               const void* wih, const void* whh, const void* bih, const void* bhh,
               const void* tw, const void* tb,
               const u32* __restrict__ flag, const u64* __restrict__ key,
               const int* __restrict__ list, const u32* __restrict__ cnt, int use_list,
               void* out, int N, int E) {
  if (use_list && (int)*cnt <= BM * (int)blockIdx.x) return;

  __shared__ __align__(16) bf16 As[BM][72];
  __shared__ __align__(16) bf16 Bs[BN][72];
  __shared__ __align__(16) float Gs[BM][132];
  __shared__ int s_node[BM], s_e[BM], s_oth[BM], s_act[BM];
  __shared__ float s_dt[BM];

  if (*flag)
    gemm_body<true>(mem, lastup, t, feat, src, dst, wih, whh, bih, bhh, tw, tb,
                    key, list, cnt, use_list, out, N, E,
                    As, Bs, Gs, s_node, s_e, s_oth, s_act, s_dt);
  else
    gemm_body<false>(mem, lastup, t, feat, src, dst, wih, whh, bih, bhh, tw, tb,
                     key, list, cnt, use_list, out, N, E,
                     As, Bs, Gs, s_node, s_e, s_oth, s_act, s_dt);
}

extern "C" void kernel_launch(void* const* d_in, const int* in_sizes, int n_in,
                              void* d_out, int out_size, void* d_ws, size_t ws_size,
                              hipStream_t stream) {
  const void* mem    = d_in[0];
  const void* lastup = d_in[1];
  const void* t      = d_in[2];
  const void* feat   = d_in[3];
  const void* tw     = d_in[4];
  const void* tb     = d_in[5];
  const void* wih    = d_in[6];
  const void* whh    = d_in[7];
  const void* bih    = d_in[8];
  const void* bhh    = d_in[9];
  const int*  src    = (const int*)d_in[10];
  const int*  dst    = (const int*)d_in[11];

  int N = in_sizes[0] / D_;
  int E = in_sizes[2];

  // ws: flag(16) + cnt(16) + key[N](8N) + list[N](4N, optional)
  //     + wpk3 (512*512 bf16 = 524288B, optional -> fallback kernel)
  char* ws = (char*)d_ws;
  size_t off = 0;
  u32* flag = (u32*)(ws + off); off += 16;
  u32* cnt  = (u32*)(ws + off); off += 16;
  u64* key  = (u64*)(ws + off); off += (size_t)N * 8;
  int* list = (int*)(ws + off); off += (size_t)N * 4;
  int use_list = (ws_size >= off) ? 1 : 0;
  bf16* wpk3 = (bf16*)(ws + off); off += (size_t)512 * 512 * 2;
  int use3 = (ws_size >= off) ? 1 : 0;

  const int thr = 256;
  int nb = (N + thr - 1) / thr;
  int eb = (2 * E + thr - 1) / thr;

  k_prep<<<dim3(nb), dim3(thr), 0, stream>>>(key, cnt, N, (const u32*)mem, (const u32*)t, flag);
  k_scat<<<dim3(eb), dim3(thr), 0, stream>>>(src, dst, t, flag, key, E);
  if (use3)
    k_pack3<<<dim3(128), dim3(thr), 0, stream>>>(wih, whh, flag, wpk3);
  k_compact<<<dim3(nb), dim3(thr), 0, stream>>>(mem, lastup, t, flag, key,
                                                list, cnt, use_list, d_out, N, E);
  if (use3) {
    int mt = (N + 31) / 32;
    k_gemm3<<<dim3(mt), dim3(thr), 0, stream>>>(
        mem, lastup, t, feat, src, dst, wpk3, bih, bhh, tw, tb,
        flag, key, list, cnt, use_list, d_out, N, E);
  } else {
    int mt = (N + BM - 1) / BM;
    k_gemm_fb<<<dim3(mt, 4), dim3(thr), 0, stream>>>(
        mem, lastup, t, feat, src, dst, wih, whh, bih, bhh, tw, tb,
        flag, key, list, cnt, use_list, d_out, N, E);
  }
}

// Round 6
// 480.186 us; speedup vs baseline: 3.7877x; 3.7877x over previous
//
#include <hip/hip_runtime.h>
#include <hip/hip_bf16.h>
#include <stdint.h>

typedef __hip_bfloat16 bf16;
typedef unsigned long long u64;
typedef unsigned int u32;
typedef short short8 __attribute__((ext_vector_type(8)));
typedef float f32x4 __attribute__((ext_vector_type(4)));

#define D_ 128   // memory dim
// fallback tile (round-0 proven kernel, reads raw weights, K=640)
#define BM 64
#define BN 128
#define BK 64
#define KFB 640
// main kernel tile
#define BM2 32

__device__ __forceinline__ float bf2f(bf16 v) { return __bfloat162float(v); }
__device__ __forceinline__ u32 fbits(float f) { union { float f; u32 u; } c; c.f = f; return c.u; }
__device__ __forceinline__ u32 pk2(float a, float b) {
  union { bf16 h; unsigned short s; } x, y;
  x.h = __float2bfloat16(a); y.h = __float2bfloat16(b);
  return (u32)x.s | ((u32)y.s << 16);
}
template<bool F32>
__device__ __forceinline__ float ldE(const void* p, size_t i) {
  return F32 ? ((const float*)p)[i] : bf2f(((const bf16*)p)[i]);
}
template<bool F32>
__device__ __forceinline__ void stE(void* p, size_t i, float v) {
  if (F32) ((float*)p)[i] = v; else ((bf16*)p)[i] = __float2bfloat16(v);
}
// load 8 source elements (bf16 or fp32) as 8 bf16 packed in a uint4
template<bool F32>
__device__ __forceinline__ uint4 ld8(const void* base, size_t elemOff) {
  if (!F32) {
    return *(const uint4*)((const bf16*)base + elemOff);
  } else {
    const float4* p = (const float4*)((const float*)base + elemOff);
    float4 v0 = p[0], v1 = p[1];
    uint4 o; o.x = pk2(v0.x, v0.y); o.y = pk2(v0.z, v0.w);
    o.z = pk2(v1.x, v1.y); o.w = pk2(v1.z, v1.w);
    return o;
  }
}
template<bool F32>
__device__ __forceinline__ void stage8(const void* base, size_t elemOff, bf16* dst) {
  *(uint4*)dst = ld8<F32>(base, elemOff);
}
// async global->LDS, 16B per lane; lds ptr must be wave-uniform
__device__ __forceinline__ void gl_lds16(const void* g, void* l) {
  __builtin_amdgcn_global_load_lds(
      (const __attribute__((address_space(1))) unsigned int*)g,
      (__attribute__((address_space(3))) unsigned int*)l, 16, 0, 0);
}

// ---- prep: zero scatter keys + cnt, sniff dtype (0 = bf16, 1 = fp32) ------
__global__ void k_prep(u64* __restrict__ key, u32* __restrict__ cnt, int N,
                       const u32* __restrict__ mem_w, const u32* __restrict__ t_w,
                       u32* __restrict__ flag) {
  int i = blockIdx.x * blockDim.x + threadIdx.x;
  if (i < N) key[i] = 0ull;
  if (i == 0) {
    *cnt = 0u;
    int ok = 1;
    for (int k = 0; k < 64; ++k) {
      u32 w = mem_w[k];
      if ((w & 0x7fffu) > 0x4300u) ok = 0;
      if (((w >> 16) & 0x7fffu) > 0x4300u) ok = 0;
    }
    for (int k = 0; k < 16; ++k) {
      u32 w = t_w[k];
      if ((w & 0xffffu) > 0x4480u) ok = 0;
      if ((w >> 16) > 0x4480u) ok = 0;
    }
    *flag = ok ? 0u : 1u;
  }
}

// ---- single scatter pass: per-node lexicographic max of (t_bits, pos+1) ---
__global__ void k_scat(const int* __restrict__ src, const int* __restrict__ dst,
                       const void* __restrict__ t, const u32* __restrict__ flag,
                       u64* __restrict__ key, int E) {
  int i = blockIdx.x * blockDim.x + threadIdx.x;
  if (i >= 2 * E) return;
  int e = (i < E) ? i : i - E;
  int node = (i < E) ? src[e] : dst[e];
  float tv = (*flag) ? ((const float*)t)[e] : bf2f(((const bf16*)t)[e]);
  u64 k = ((u64)fbits(tv) << 32) | (u64)(u32)(i + 1);  // t >= 0: bit order == value order
  atomicMax(&key[node], k);
}

// ---- pack FOLDED weights W'' (K=512) into Round-1's swizzled tile layout.
// Fold (verified R5): X' cols [512,640) == cols [0,128) (h = mem[node]), so
// w_hh's r/z parts add into W'' at k<128; grp2 (i_n) = wih only; grp3 (h_n)
// nonzero only k<128 (whh part).
// Layout (verified R1): tile=kc*4+by (32 tiles), 16B-unit index (j*8+s)^(j&7).
__global__ void k_pack2(const void* __restrict__ wih, const void* __restrict__ whh,
                        const u32* __restrict__ flag, bf16* __restrict__ wpk) {
  int gid = blockIdx.x * 256 + threadIdx.x;
  if (gid >= 32768) return;                // 32 tiles x 1024 16B-groups
  int tile = gid >> 10, r = gid & 1023;
  int j = r >> 3, s = r & 7;
  int kc = tile >> 2, by = tile & 3;
  int kglob = kc * 64 + s * 8;
  int grp = j >> 5, gi = j & 31, gidx = 32 * by + gi;
  bool F = (*flag != 0);
  float f[8];
#pragma unroll
  for (int q = 0; q < 8; ++q) {
    int k = kglob + q;
    float v = 0.f;
    if (grp < 3) {
      int srow = grp * 128 + gidx;
      v = F ? ldE<true>(wih, (size_t)srow * 512 + k) : ldE<false>(wih, (size_t)srow * 512 + k);
      if (k < 128 && grp < 2)
        v += F ? ldE<true>(whh, (size_t)srow * 128 + k) : ldE<false>(whh, (size_t)srow * 128 + k);
    } else if (k < 128) {
      v = F ? ldE<true>(whh, (size_t)(256 + gidx) * 128 + k)
            : ldE<false>(whh, (size_t)(256 + gidx) * 128 + k);
    }
    f[q] = v;
  }
  uint4 o; o.x = pk2(f[0], f[1]); o.y = pk2(f[2], f[3]);
  o.z = pk2(f[4], f[5]); o.w = pk2(f[6], f[7]);
  ((uint4*)wpk)[(size_t)tile * 1024 + ((j * 8 + s) ^ (j & 7))] = o;
}

// ---- compact: passthrough inactive rows, out_last for all, optional list.
// List append via block-aggregated atomic (1 atomic/block).
template<bool F32>
__device__ __forceinline__ void compact_body(int n, bool nvalid,
                                             const void* mem, const void* lastup,
                                             const void* t, const u64* key,
                                             int* list, u32* cnt, int use_list,
                                             void* out, int N, int E, u32* s_wb) {
  u32 b = 0;
  if (nvalid) b = (u32)key[n];
  bool active = nvalid && (b != 0u);
  if (use_list) {
    u64 mask = __ballot(active);
    int lane = threadIdx.x & 63, w = threadIdx.x >> 6;
    if (lane == 0) s_wb[w] = (u32)__popcll(mask);
    __syncthreads();
    if (threadIdx.x == 0) {
      u32 tot = s_wb[0] + s_wb[1] + s_wb[2] + s_wb[3];
      u32 base = tot ? atomicAdd(cnt, tot) : 0u;
      u32 acc0 = base;
      for (int i = 0; i < 4; ++i) { u32 c = s_wb[i]; s_wb[i] = acc0; acc0 += c; }
    }
    __syncthreads();
    if (active) {
      u32 idx = s_wb[w] + (u32)__popcll(mask & ((1ull << lane) - 1ull));
      list[idx] = n;
    }
  }
  if (!nvalid) return;
  if (active) {
    int pos = (int)(b - 1u);
    int e = (pos < E) ? pos : pos - E;
    stE<F32>(out, (size_t)N * D_ + n, ldE<F32>(t, e));
  } else {
    if (F32) {
      const float4* s = (const float4*)((const float*)mem + (size_t)n * D_);
      float4* d = (float4*)((float*)out + (size_t)n * D_);
#pragma unroll
      for (int i = 0; i < 32; ++i) d[i] = s[i];
    } else {
      const uint4* s = (const uint4*)((const bf16*)mem + (size_t)n * D_);
      uint4* d = (uint4*)((bf16*)out + (size_t)n * D_);
#pragma unroll
      for (int i = 0; i < 16; ++i) d[i] = s[i];
    }
    stE<F32>(out, (size_t)N * D_ + n, ldE<F32>(lastup, n));
  }
}
__global__ void k_compact(const void* mem, const void* lastup, const void* t,
                          const u32* __restrict__ flag, const u64* __restrict__ key,
                          int* list, u32* cnt, int use_list,
                          void* out, int N, int E) {
  __shared__ u32 s_wb[4];
  int n = blockIdx.x * blockDim.x + threadIdx.x;
  bool nvalid = (n < N);
  if (*flag) compact_body<true>(n, nvalid, mem, lastup, t, key, list, cnt, use_list, out, N, E, s_wb);
  else       compact_body<false>(n, nvalid, mem, lastup, t, key, list, cnt, use_list, out, N, E, s_wb);
}

// ============================================================================
// k_gemm2 (Round-1 verified structure + K-fold): one block = 32 rows x all
// 512 gate-cols; 8 kc x 4 by = 32 phases; A gathered once, cosf once.
// B staged async (global_load_lds) from folded/packed wpk, double-buffered one
// phase ahead; per-phase __syncthreads. Wave 3 (h_n) has zero B for kc>=2 ->
// skips its staging, LDS reads, and MFMAs there (its B quarter is private).
// ============================================================================
template<bool F32>
__device__ __forceinline__ uint4 a_fetch(int kcn, int tid,
    const void* mem, const void* feat,
    const int* s_node, const int* s_e, const int* s_oth,
    const float* s_dt, const float* s_tw, const float* s_tb) {
  int r = tid >> 3, s = tid & 7;
  int k0 = kcn * 64 + s * 8;       // each kc maps to exactly one source region
  if (k0 < 128) return ld8<F32>(mem, (size_t)s_node[r] * D_ + k0);
  if (k0 < 256) return ld8<F32>(mem, (size_t)s_oth[r] * D_ + (k0 - 128));
  if (k0 < 384) {
    float dtv = s_dt[r];
    float f[8];
#pragma unroll
    for (int q = 0; q < 8; ++q) {
      int j = k0 - 256 + q;
      f[q] = cosf(fmaf(dtv, s_tw[j], s_tb[j]));
    }
    uint4 o; o.x = pk2(f[0], f[1]); o.y = pk2(f[2], f[3]);
    o.z = pk2(f[4], f[5]); o.w = pk2(f[6], f[7]);
    return o;
  }
  return ld8<F32>(feat, (size_t)s_e[r] * D_ + (k0 - 384));
}

// stage one 128x64 bf16 B-tile (16KB): 4 x global_load_lds(16B) per thread.
// Wave w writes ONLY its own quarter and later reads only that quarter.
__device__ __forceinline__ void b_issue(const bf16* __restrict__ wpk, int tile,
                                        bf16* BsBuf, int tid) {
  int w = tid >> 6;
  const bf16* g = wpk + (size_t)tile * 8192 + w * 2048 + (tid & 63) * 8;
  bf16* l = BsBuf + w * 2048;      // wave-uniform; HW adds lane*16B
#pragma unroll
  for (int i = 0; i < 4; ++i)
    gl_lds16(g + i * 512, l + i * 512);
}

template<bool F32>
__device__ __forceinline__ void gemm2_body(
    const void* mem, const void* lastup, const void* t, const void* feat,
    const int* __restrict__ src, const int* __restrict__ dst,
    const bf16* __restrict__ wpk,
    const void* bih, const void* bhh, const void* tw, const void* tb,
    const u64* __restrict__ key, const int* __restrict__ list,
    const u32* __restrict__ cnt, int use_list,
    void* out, int N, int E,
    char* smem, int* s_node, int* s_e, int* s_oth, int* s_act,
    float* s_dt, float* s_tw, float* s_tb) {
  const int tid = threadIdx.x;
  const int bx = blockIdx.x;
  bf16 (*As)[BM2][72] = (bf16 (*)[BM2][72])smem;          //  9216 B (2 bufs)
  bf16* BsBase = (bf16*)(smem + 9216);                     // 32768 B (2 bufs)
  float (*Gs)[133] = (float (*)[133])smem;                 // overlay (epilogue)

  b_issue(wpk, 0, BsBase, tid);    // start weight tile 0 ASAP

  if (tid < BM2) {
    int r = tid, row = BM2 * bx + r, node = -1;
    if (use_list) { int c = (int)*cnt; if (row < c) node = list[row]; }
    else if (row < N) node = row;
    int act = 0, e = 0, oth = 0; float dtv = 0.f;
    if (node >= 0) {
      u32 b = (u32)key[node];
      if (b) {
        act = 1;
        int pos = (int)(b - 1u);
        if (pos < E) { e = pos; oth = dst[e]; } else { e = pos - E; oth = src[e]; }
        dtv = ldE<F32>(t, e) - ldE<F32>(lastup, node);
      }
    }
    if (node < 0) node = 0;
    s_node[r] = node; s_e[r] = e; s_oth[r] = oth; s_act[r] = act; s_dt[r] = dtv;
  }
  if (tid < 128) s_tw[tid] = ldE<F32>(tw, tid);
  else           s_tb[tid - 128] = ldE<F32>(tb, tid - 128);
  __syncthreads();

  {  // stage A(kc=0)
    uint4 a0 = a_fetch<F32>(0, tid, mem, feat, s_node, s_e, s_oth, s_dt, s_tw, s_tb);
    *(uint4*)&As[0][tid >> 3][(tid & 7) * 8] = a0;
  }
  __syncthreads();

  const int w = tid >> 6, l = tid & 63;
  const int mrow = l & 15, quad = l >> 4;
  const bool w3 = (w == 3);
  f32x4 acc[4][2][2];   // [by][mi][ni]
#pragma unroll
  for (int by = 0; by < 4; ++by)
#pragma unroll
    for (int mi = 0; mi < 2; ++mi)
#pragma unroll
      for (int ni = 0; ni < 2; ++ni) acc[by][mi][ni] = (f32x4){0.f, 0.f, 0.f, 0.f};

  uint4 apre = (uint4){0u, 0u, 0u, 0u};
#pragma unroll 1
  for (int kc = 0; kc < 8; ++kc) {
    const int ka = kc & 1;
    short8 a[2][2];
#pragma unroll
    for (int by = 0; by < 4; ++by) {            // phase = kc*4+by; Bs buf = by&1
      const int tile = kc * 4 + by;
      if (by == 0) {
        if (kc + 1 < 8)
          apre = a_fetch<F32>(kc + 1, tid, mem, feat, s_node, s_e, s_oth, s_dt, s_tw, s_tb);
      }
      if (tile + 1 < 32 && !(w3 && (tile + 1) >= 8))
        b_issue(wpk, tile + 1, BsBase + (((by & 1) ^ 1) << 13), tid);
      if (by == 0) {
#pragma unroll
        for (int ks2 = 0; ks2 < 2; ++ks2)
#pragma unroll
          for (int mi = 0; mi < 2; ++mi)
            a[ks2][mi] = *(const short8*)((const char*)&As[ka][0][0] +
                             (16 * mi + mrow) * 144 + ks2 * 64 + quad * 16);
      }
      if (!(w3 && kc >= 2)) {                   // h_n group: B==0 for kc>=2
        const char* Bsb = (const char*)(BsBase + ((by & 1) << 13));
        short8 b[2][2];
#pragma unroll
        for (int ks2 = 0; ks2 < 2; ++ks2)
#pragma unroll
          for (int ni = 0; ni < 2; ++ni) {
            int j = 32 * w + 16 * ni + mrow;
            int off = (j * 128 + ks2 * 64 + quad * 16) ^ ((j & 7) << 4);
            b[ks2][ni] = *(const short8*)(Bsb + off);
          }
        __builtin_amdgcn_s_setprio(1);
#pragma unroll
        for (int ks2 = 0; ks2 < 2; ++ks2)
#pragma unroll
          for (int mi = 0; mi < 2; ++mi)
#pragma unroll
            for (int ni = 0; ni < 2; ++ni)
              acc[by][mi][ni] = __builtin_amdgcn_mfma_f32_16x16x32_bf16(
                  a[ks2][mi], b[ks2][ni], acc[by][mi][ni], 0, 0, 0);
        __builtin_amdgcn_s_setprio(0);
      }
      if (by == 3 && kc + 1 < 8)
        *(uint4*)&As[ka ^ 1][tid >> 3][(tid & 7) * 8] = apre;
      __syncthreads();   // drains vmcnt: next B tile + A prefetch landed
    }
  }

  // ---- GRU epilogue per by (Gs overlays the dead As/Bs region) ----
#pragma unroll
  for (int by = 0; by < 4; ++by) {
#pragma unroll
    for (int mi = 0; mi < 2; ++mi)
#pragma unroll
      for (int ni = 0; ni < 2; ++ni)
#pragma unroll
        for (int reg = 0; reg < 4; ++reg)
          Gs[16 * mi + quad * 4 + reg][32 * w + 16 * ni + mrow] = acc[by][mi][ni][reg];
    __syncthreads();
    {
      int r = tid >> 3, giB = (tid & 7) * 4;
      if (s_act[r]) {
        int node = s_node[r];
#pragma unroll
        for (int q = 0; q < 4; ++q) {
          int gi = giB + q, gidx = 32 * by + gi;
          float rp  = Gs[r][gi]      + ldE<F32>(bih, gidx)       + ldE<F32>(bhh, gidx);
          float zp  = Gs[r][32 + gi] + ldE<F32>(bih, 128 + gidx) + ldE<F32>(bhh, 128 + gidx);
          float inp = Gs[r][64 + gi] + ldE<F32>(bih, 256 + gidx);
          float hnp = Gs[r][96 + gi] + ldE<F32>(bhh, 256 + gidx);
          float rg = 1.f / (1.f + expf(-rp));
          float zg = 1.f / (1.f + expf(-zp));
          float ng = tanhf(inp + rg * hnp);
          float h = ldE<F32>(mem, (size_t)node * D_ + gidx);
          stE<F32>(out, (size_t)node * D_ + gidx, (1.f - zg) * ng + zg * h);
        }
      }
    }
    __syncthreads();
  }
}

__global__ __launch_bounds__(256, 3)
void k_gemm2(const void* mem, const void* lastup, const void* t, const void* feat,
             const int* src, const int* dst, const bf16* wpk,
             const void* bih, const void* bhh, const void* tw, const void* tb,
             const u32* __restrict__ flag, const u64* __restrict__ key,
             const int* __restrict__ list, const u32* __restrict__ cnt, int use_list,
             void* out, int N, int E) {
  if (use_list && (int)*cnt <= BM2 * (int)blockIdx.x) return;  // uniform, pre-barrier
  __shared__ __align__(16) char smem[41984];   // As 9216 + Bs 2x16384; Gs overlay 17024
  __shared__ int s_node[BM2], s_e[BM2], s_oth[BM2], s_act[BM2];
  __shared__ float s_dt[BM2], s_tw[128], s_tb[128];
  if (*flag)
    gemm2_body<true>(mem, lastup, t, feat, src, dst, wpk, bih, bhh, tw, tb,
                     key, list, cnt, use_list, out, N, E,
                     smem, s_node, s_e, s_oth, s_act, s_dt, s_tw, s_tb);
  else
    gemm2_body<false>(mem, lastup, t, feat, src, dst, wpk, bih, bhh, tw, tb,
                      key, list, cnt, use_list, out, N, E,
                      smem, s_node, s_e, s_oth, s_act, s_dt, s_tw, s_tb);
}

// ============================================================================
// FALLBACK (tiny ws): round-0 proven kernel, grid (mtiles,4), raw weights K=640.
// ============================================================================
template<bool F32>
__device__ __forceinline__ void gemm_body(
    const void* mem, const void* lastup, const void* t, const void* feat,
    const int* __restrict__ src, const int* __restrict__ dst,
    const void* wih, const void* whh, const void* bih, const void* bhh,
    const void* tw, const void* tb,
    const u64* __restrict__ key, const int* __restrict__ list,
    const u32* __restrict__ cnt, int use_list,
    void* out, int N, int E,
    bf16 (*As)[72], bf16 (*Bs)[72], float (*Gs)[132],
    int* s_node, int* s_e, int* s_oth, int* s_act, float* s_dt) {
  const int tid = threadIdx.x;
  const int bx = blockIdx.x, by = blockIdx.y;

  if (tid < BM) {
    int r = tid;
    int row = BM * bx + r;
    int node = -1;
    if (use_list) { int c = (int)*cnt; if (row < c) node = list[row]; }
    else if (row < N) node = row;
    int act = 0, e = 0, oth = 0; float dtv = 0.f;
    if (node >= 0) {
      u32 b = (u32)key[node];
      if (b) {
        act = 1;
        int pos = (int)(b - 1u);
        if (pos < E) { e = pos; oth = dst[e]; } else { e = pos - E; oth = src[e]; }
        dtv = ldE<F32>(t, e) - ldE<F32>(lastup, node);
      }
    }
    if (node < 0) node = 0;
    s_node[r] = node; s_e[r] = e; s_oth[r] = oth; s_act[r] = act; s_dt[r] = dtv;
  }

  const int w = tid >> 6, l = tid & 63;
  const int mrow = l & 15, quad = l >> 4;
  f32x4 acc[4][2];
#pragma unroll
  for (int mi = 0; mi < 4; ++mi)
#pragma unroll
    for (int ni = 0; ni < 2; ++ni) acc[mi][ni] = (f32x4){0.f, 0.f, 0.f, 0.f};

#pragma unroll 1
  for (int kc = 0; kc < KFB / BK; ++kc) {
    __syncthreads();
#pragma unroll
    for (int it = 0; it < 2; ++it) {
      int task = tid + 256 * it;
      int r = task >> 3, s = task & 7;
      int k0 = kc * BK + s * 8;
      bf16* dstp = &As[r][s * 8];
      if (k0 < 128)       stage8<F32>(mem,  (size_t)s_node[r] * D_ + k0, dstp);
      else if (k0 < 256)  stage8<F32>(mem,  (size_t)s_oth[r] * D_ + (k0 - 128), dstp);
      else if (k0 < 384) {
        float dtv = s_dt[r];
        float f[8];
#pragma unroll
        for (int q = 0; q < 8; ++q) {
          int j = k0 - 256 + q;
          f[q] = cosf(fmaf(dtv, ldE<F32>(tw, j), ldE<F32>(tb, j)));
        }
        uint4 o; o.x = pk2(f[0], f[1]); o.y = pk2(f[2], f[3]);
        o.z = pk2(f[4], f[5]); o.w = pk2(f[6], f[7]);
        *(uint4*)dstp = o;
      }
      else if (k0 < 512)  stage8<F32>(feat, (size_t)s_e[r] * D_ + (k0 - 384), dstp);
      else                stage8<F32>(mem,  (size_t)s_node[r] * D_ + (k0 - 512), dstp);
    }
#pragma unroll
    for (int it = 0; it < 4; ++it) {
      int task = tid + 256 * it;
      int j = task >> 3, s = task & 7;
      int k0 = kc * BK + s * 8;
      int grp = j >> 5, gi = j & 31;
      int gidx = 32 * by + gi;
      bf16* dstp = &Bs[j][s * 8];
      if (k0 < 512) {
        if (grp == 3) { *(uint4*)dstp = (uint4){0, 0, 0, 0}; }
        else {
          int srow = (grp == 0) ? gidx : (grp == 1) ? 128 + gidx : 256 + gidx;
          stage8<F32>(wih, (size_t)srow * 512 + k0, dstp);
        }
      } else {
        if (grp == 2) { *(uint4*)dstp = (uint4){0, 0, 0, 0}; }
        else {
          int srow = (grp == 0) ? gidx : (grp == 1) ? 128 + gidx : 256 + gidx;
          stage8<F32>(whh, (size_t)srow * D_ + (k0 - 512), dstp);
        }
      }
    }
    __syncthreads();
#pragma unroll
    for (int ks = 0; ks < BK; ks += 32) {
      short8 a[4], b[2];
#pragma unroll
      for (int mi = 0; mi < 4; ++mi)
        a[mi] = *(const short8*)&As[16 * mi + mrow][ks + quad * 8];
#pragma unroll
      for (int ni = 0; ni < 2; ++ni)
        b[ni] = *(const short8*)&Bs[32 * w + 16 * ni + mrow][ks + quad * 8];
#pragma unroll
      for (int mi = 0; mi < 4; ++mi)
#pragma unroll
        for (int ni = 0; ni < 2; ++ni)
          acc[mi][ni] = __builtin_amdgcn_mfma_f32_16x16x32_bf16(a[mi], b[ni], acc[mi][ni], 0, 0, 0);
    }
  }

#pragma unroll
  for (int mi = 0; mi < 4; ++mi)
#pragma unroll
    for (int ni = 0; ni < 2; ++ni)
#pragma unroll
      for (int reg = 0; reg < 4; ++reg)
        Gs[16 * mi + quad * 4 + reg][32 * w + 16 * ni + mrow] = acc[mi][ni][reg];
  __syncthreads();

  {
    int r = tid >> 2;
    int giB = (tid & 3) * 8;
    if (s_act[r]) {
      int node = s_node[r];
#pragma unroll
      for (int q = 0; q < 8; ++q) {
        int gi = giB + q;
        int gidx = 32 * by + gi;
        float rp  = Gs[r][gi]       + ldE<F32>(bih, gidx)       + ldE<F32>(bhh, gidx);
        float zp  = Gs[r][32 + gi]  + ldE<F32>(bih, 128 + gidx) + ldE<F32>(bhh, 128 + gidx);
        float inp = Gs[r][64 + gi]  + ldE<F32>(bih, 256 + gidx);
        float hnp = Gs[r][96 + gi]  + ldE<F32>(bhh, 256 + gidx);
        float rg = 1.f / (1.f + expf(-rp));
        float zg = 1.f / (1.f + expf(-zp));
        float ng = tanhf(inp + rg * hnp);
        float h = ldE<F32>(mem, (size_t)node * D_ + gidx);
        stE<F32>(out, (size_t)node * D_ + gidx, (1.f - zg) * ng + zg * h);
      }
    }
  }
}

__global__ __launch_bounds__(256)
void k_gemm_fb(const void* mem, const void* lastup, const void* t, const void* feat,
               const int* src, const int* dst,
               const void* wih, const void* whh, const void* bih, const void* bhh,
               const void* tw, const void* tb,
               const u32* __restrict__ flag, const u64* __restrict__ key,
               const int* __restrict__ list, const u32* __restrict__ cnt, int use_list,
               void* out, int N, int E) {
  if (use_list && (int)*cnt <= BM * (int)blockIdx.x) return;

  __shared__ __align__(16) bf16 As[BM][72];
  __shared__ __align__(16) bf16 Bs[BN][72];
  __shared__ __align__(16) float Gs[BM][132];
  __shared__ int s_node[BM], s_e[BM], s_oth[BM], s_act[BM];
  __shared__ float s_dt[BM];

  if (*flag)
    gemm_body<true>(mem, lastup, t, feat, src, dst, wih, whh, bih, bhh, tw, tb,
                    key, list, cnt, use_list, out, N, E,
                    As, Bs, Gs, s_node, s_e, s_oth, s_act, s_dt);
  else
    gemm_body<false>(mem, lastup, t, feat, src, dst, wih, whh, bih, bhh, tw, tb,
                     key, list, cnt, use_list, out, N, E,
                     As, Bs, Gs, s_node, s_e, s_oth, s_act, s_dt);
}

extern "C" void kernel_launch(void* const* d_in, const int* in_sizes, int n_in,
                              void* d_out, int out_size, void* d_ws, size_t ws_size,
                              hipStream_t stream) {
  const void* mem    = d_in[0];
  const void* lastup = d_in[1];
  const void* t      = d_in[2];
  const void* feat   = d_in[3];
  const void* tw     = d_in[4];
  const void* tb     = d_in[5];
  const void* wih    = d_in[6];
  const void* whh    = d_in[7];
  const void* bih    = d_in[8];
  const void* bhh    = d_in[9];
  const int*  src    = (const int*)d_in[10];
  const int*  dst    = (const int*)d_in[11];

  int N = in_sizes[0] / D_;
  int E = in_sizes[2];

  // ws: flag(16) + cnt(16) + key[N](8N) + list[N](4N, optional)
  //     + wpk (32 tiles x 8192 bf16 = 524288B, optional -> fallback kernel)
  char* ws = (char*)d_ws;
  size_t off = 0;
  u32* flag = (u32*)(ws + off); off += 16;
  u32* cnt  = (u32*)(ws + off); off += 16;
  u64* key  = (u64*)(ws + off); off += (size_t)N * 8;
  int* list = (int*)(ws + off); off += (size_t)N * 4;
  int use_list = (ws_size >= off) ? 1 : 0;
  bf16* wpk = (bf16*)(ws + off); off += (size_t)32 * 8192 * 2;
  int use2 = (ws_size >= off) ? 1 : 0;

  const int thr = 256;
  int nb = (N + thr - 1) / thr;
  int eb = (2 * E + thr - 1) / thr;

  k_prep<<<dim3(nb), dim3(thr), 0, stream>>>(key, cnt, N, (const u32*)mem, (const u32*)t, flag);
  k_scat<<<dim3(eb), dim3(thr), 0, stream>>>(src, dst, t, flag, key, E);
  if (use2)
    k_pack2<<<dim3(128), dim3(thr), 0, stream>>>(wih, whh, flag, wpk);
  k_compact<<<dim3(nb), dim3(thr), 0, stream>>>(mem, lastup, t, flag, key,
                                                list, cnt, use_list, d_out, N, E);
  if (use2) {
    int mt = (N + BM2 - 1) / BM2;
    k_gemm2<<<dim3(mt), dim3(thr), 0, stream>>>(
        mem, lastup, t, feat, src, dst, wpk, bih, bhh, tw, tb,
        flag, key, list, cnt, use_list, d_out, N, E);
  } else {
    int mt = (N + BM - 1) / BM;
    k_gemm_fb<<<dim3(mt, 4), dim3(thr), 0, stream>>>(
        mem, lastup, t, feat, src, dst, wih, whh, bih, bhh, tw, tb,
        flag, key, list, cnt, use_list, d_out, N, E);
  }
}

// Round 9
// 467.856 us; speedup vs baseline: 3.8875x; 1.0264x over previous
//
#include <hip/hip_runtime.h>
#include <hip/hip_bf16.h>
#include <stdint.h>

typedef __hip_bfloat16 bf16;
typedef unsigned long long u64;
typedef unsigned int u32;
typedef short short8 __attribute__((ext_vector_type(8)));
typedef float f32x4 __attribute__((ext_vector_type(4)));

#define D_ 128   // memory dim
// fallback tile (round-0 proven kernel, reads raw weights, K=640)
#define BM 64
#define BN 128
#define BK 64
#define KFB 640
// main kernel tile
#define BM2 32

#define VMWAIT(n) asm volatile("s_waitcnt vmcnt(" #n ")" ::: "memory")

__device__ __forceinline__ float bf2f(bf16 v) { return __bfloat162float(v); }
__device__ __forceinline__ u32 fbits(float f) { union { float f; u32 u; } c; c.f = f; return c.u; }
__device__ __forceinline__ u32 pk2(float a, float b) {
  union { bf16 h; unsigned short s; } x, y;
  x.h = __float2bfloat16(a); y.h = __float2bfloat16(b);
  return (u32)x.s | ((u32)y.s << 16);
}
template<bool F32>
__device__ __forceinline__ float ldE(const void* p, size_t i) {
  return F32 ? ((const float*)p)[i] : bf2f(((const bf16*)p)[i]);
}
template<bool F32>
__device__ __forceinline__ void stE(void* p, size_t i, float v) {
  if (F32) ((float*)p)[i] = v; else ((bf16*)p)[i] = __float2bfloat16(v);
}
// load 8 source elements (bf16 or fp32) as 8 bf16 packed in a uint4
template<bool F32>
__device__ __forceinline__ uint4 ld8(const void* base, size_t elemOff) {
  if (!F32) {
    return *(const uint4*)((const bf16*)base + elemOff);
  } else {
    const float4* p = (const float4*)((const float*)base + elemOff);
    float4 v0 = p[0], v1 = p[1];
    uint4 o; o.x = pk2(v0.x, v0.y); o.y = pk2(v0.z, v0.w);
    o.z = pk2(v1.x, v1.y); o.w = pk2(v1.z, v1.w);
    return o;
  }
}
template<bool F32>
__device__ __forceinline__ void stage8(const void* base, size_t elemOff, bf16* dst) {
  *(uint4*)dst = ld8<F32>(base, elemOff);
}
// async global->LDS, 16B per lane; lds ptr must be wave-uniform
__device__ __forceinline__ void gl_lds16(const void* g, void* l) {
  __builtin_amdgcn_global_load_lds(
      (const __attribute__((address_space(1))) unsigned int*)g,
      (__attribute__((address_space(3))) unsigned int*)l, 16, 0, 0);
}

// ---- dtype sniff (device fn): 0 = bf16, 1 = fp32 --------------------------
__device__ __forceinline__ u32 sniff_dtype(const u32* mem_w, const u32* t_w) {
  int ok = 1;
  for (int k = 0; k < 64; ++k) {
    u32 w = mem_w[k];
    if ((w & 0x7fffu) > 0x4300u) ok = 0;
    if (((w >> 16) & 0x7fffu) > 0x4300u) ok = 0;
  }
  for (int k = 0; k < 16; ++k) {
    u32 w = t_w[k];
    if ((w & 0xffffu) > 0x4480u) ok = 0;
    if ((w >> 16) > 0x4480u) ok = 0;
  }
  return ok ? 0u : 1u;
}

// ---- merged prep (zero keys, cnt, flag) + weight pack (blocks < 128) ------
// Pack writes FOLDED weights W'' (K=512) into the R1-verified swizzled tile
// layout: tile=kc*4+by (32 tiles x 8192 bf16), 16B-unit (j*8+s)^(j&7).
//   grp0 (r):  wih[gidx][k]      + (k<128 ? whh[gidx][k] : 0)
//   grp1 (z):  wih[128+gidx][k]  + (k<128 ? whh[128+gidx][k] : 0)
//   grp2 (in): wih[256+gidx][k]
//   grp3 (hn): k<128 ? whh[256+gidx][k] : 0
__global__ void k_preppack(u64* __restrict__ key, u32* __restrict__ cnt, int N,
                           const u32* __restrict__ mem_w, const u32* __restrict__ t_w,
                           u32* __restrict__ flag,
                           const void* __restrict__ wih, const void* __restrict__ whh,
                           bf16* __restrict__ wpk, int do_pack) {
  __shared__ u32 s_ok;
  int i = blockIdx.x * 256 + threadIdx.x;
  if (i < N) key[i] = 0ull;
  if (i == 0) { *cnt = 0u; *flag = sniff_dtype(mem_w, t_w); }
  if (do_pack && blockIdx.x < 128) {
    if (threadIdx.x == 0) s_ok = sniff_dtype(mem_w, t_w);
    __syncthreads();
    bool F = (s_ok != 0);
    int gid = blockIdx.x * 256 + threadIdx.x;   // 32768 units, 1/thread
    int tile = gid >> 10, r = gid & 1023;
    int j = r >> 3, s = r & 7;
    int kc = tile >> 2, by = tile & 3;
    int kglob = kc * 64 + s * 8;
    int grp = j >> 5, gi = j & 31, gidx = 32 * by + gi;
    float f[8];
#pragma unroll
    for (int q = 0; q < 8; ++q) {
      int k = kglob + q;
      float v = 0.f;
      if (grp < 3) {
        int srow = grp * 128 + gidx;
        v = F ? ldE<true>(wih, (size_t)srow * 512 + k) : ldE<false>(wih, (size_t)srow * 512 + k);
        if (k < 128 && grp < 2)
          v += F ? ldE<true>(whh, (size_t)srow * 128 + k) : ldE<false>(whh, (size_t)srow * 128 + k);
      } else if (k < 128) {
        v = F ? ldE<true>(whh, (size_t)(256 + gidx) * 128 + k)
              : ldE<false>(whh, (size_t)(256 + gidx) * 128 + k);
      }
      f[q] = v;
    }
    uint4 o; o.x = pk2(f[0], f[1]); o.y = pk2(f[2], f[3]);
    o.z = pk2(f[4], f[5]); o.w = pk2(f[6], f[7]);
    ((uint4*)wpk)[(size_t)tile * 1024 + ((j * 8 + s) ^ (j & 7))] = o;
  }
}

// ---- single scatter pass: per-node lexicographic max of (t_bits, pos+1) ---
__global__ void k_scat(const int* __restrict__ src, const int* __restrict__ dst,
                       const void* __restrict__ t, const u32* __restrict__ flag,
                       u64* __restrict__ key, int E) {
  int i = blockIdx.x * blockDim.x + threadIdx.x;
  if (i >= 2 * E) return;
  int e = (i < E) ? i : i - E;
  int node = (i < E) ? src[e] : dst[e];
  float tv = (*flag) ? ((const float*)t)[e] : bf2f(((const bf16*)t)[e]);
  u64 k = ((u64)fbits(tv) << 32) | (u64)(u32)(i + 1);  // t >= 0: bit order == value order
  atomicMax(&key[node], k);
}

// ---- compact: passthrough inactive rows, out_last for all, optional list.
template<bool F32>
__device__ __forceinline__ void compact_body(int n, bool nvalid,
                                             const void* mem, const void* lastup,
                                             const void* t, const u64* key,
                                             int* list, u32* cnt, int use_list,
                                             void* out, int N, int E, u32* s_wb) {
  u32 b = 0;
  if (nvalid) b = (u32)key[n];
  bool active = nvalid && (b != 0u);
  if (use_list) {
    u64 mask = __ballot(active);
    int lane = threadIdx.x & 63, w = threadIdx.x >> 6;
    if (lane == 0) s_wb[w] = (u32)__popcll(mask);
    __syncthreads();
    if (threadIdx.x == 0) {
      u32 tot = s_wb[0] + s_wb[1] + s_wb[2] + s_wb[3];
      u32 base = tot ? atomicAdd(cnt, tot) : 0u;
      u32 acc0 = base;
      for (int i = 0; i < 4; ++i) { u32 c = s_wb[i]; s_wb[i] = acc0; acc0 += c; }
    }
    __syncthreads();
    if (active) {
      u32 idx = s_wb[w] + (u32)__popcll(mask & ((1ull << lane) - 1ull));
      list[idx] = n;
    }
  }
  if (!nvalid) return;
  if (active) {
    int pos = (int)(b - 1u);
    int e = (pos < E) ? pos : pos - E;
    stE<F32>(out, (size_t)N * D_ + n, ldE<F32>(t, e));
  } else {
    if (F32) {
      const float4* s = (const float4*)((const float*)mem + (size_t)n * D_);
      float4* d = (float4*)((float*)out + (size_t)n * D_);
#pragma unroll
      for (int i = 0; i < 32; ++i) d[i] = s[i];
    } else {
      const uint4* s = (const uint4*)((const bf16*)mem + (size_t)n * D_);
      uint4* d = (uint4*)((bf16*)out + (size_t)n * D_);
#pragma unroll
      for (int i = 0; i < 16; ++i) d[i] = s[i];
    }
    stE<F32>(out, (size_t)N * D_ + n, ldE<F32>(lastup, n));
  }
}
__global__ void k_compact(const void* mem, const void* lastup, const void* t,
                          const u32* __restrict__ flag, const u64* __restrict__ key,
                          int* list, u32* cnt, int use_list,
                          void* out, int N, int E) {
  __shared__ u32 s_wb[4];
  int n = blockIdx.x * blockDim.x + threadIdx.x;
  bool nvalid = (n < N);
  if (*flag) compact_body<true>(n, nvalid, mem, lastup, t, key, list, cnt, use_list, out, N, E, s_wb);
  else       compact_body<false>(n, nvalid, mem, lastup, t, key, list, cnt, use_list, out, N, E, s_wb);
}

// ============================================================================
// k_gemm2 (R6 structure + counted-vmcnt, barrier only per kc):
// 32 rows x 512 cols, K=512 folded, 8 kc x 4 by = 32 phases.
// 2 B LDS buffers; phase p reads B(p) from buf[p&1], then (after MFMA, own
// ds_reads retired) issues B(p+2) into the same buffer. Waves are uniform
// (wave3 stages/MFMAs its zero tiles). Cross-wave hazard is ONLY the As
// handoff -> one lgkmcnt(0)+s_barrier per kc (8 total, vmcnt NOT drained).
// Exact per-wave FIFO counts (A issued at by0 step1, B(p+2) at step5):
//   by0/by1: vmcnt(5) for kc in {0,1,2,5,6} (A load in flight; f32: 6), else 4
//   by2: vmcnt(4);  by3: vmcnt(4) (kc7: 0)
// ============================================================================
struct AR { uint4 lo, hi; };

template<bool F32>
__device__ __forceinline__ AR a_fetch_raw(int kcn, int tid,
    const void* mem, const void* feat,
    const int* s_node, const int* s_e, const int* s_oth,
    const float* s_dt, const float* s_twb) {
  int r = tid >> 3, s = tid & 7;
  int k0 = kcn * 64 + s * 8;       // each kc maps to exactly one source region
  AR a;
  if (k0 >= 256 && k0 < 384) {     // time-encoding: pure VALU, already packed
    float dtv = s_dt[r];
    float f[8];
#pragma unroll
    for (int q = 0; q < 8; ++q) {
      int j = k0 - 256 + q;
      f[q] = cosf(fmaf(dtv, s_twb[j], s_twb[128 + j]));
    }
    a.lo.x = pk2(f[0], f[1]); a.lo.y = pk2(f[2], f[3]);
    a.lo.z = pk2(f[4], f[5]); a.lo.w = pk2(f[6], f[7]);
    a.hi = a.lo;
    return a;
  }
  const void* base = mem;
  size_t eo;
  if (k0 < 128)       eo = (size_t)s_node[r] * D_ + k0;
  else if (k0 < 256)  eo = (size_t)s_oth[r] * D_ + (k0 - 128);
  else                { base = feat; eo = (size_t)s_e[r] * D_ + (k0 - 384); }
  if (F32) {
    const uint4* p = (const uint4*)((const float*)base + eo);
    a.lo = p[0]; a.hi = p[1];              // raw fp32 bits, 2 vmcnt entries
  } else {
    a.lo = *(const uint4*)((const bf16*)base + eo);  // 1 vmcnt entry
    a.hi = a.lo;
  }
  return a;
}
template<bool F32>
__device__ __forceinline__ uint4 a_pack(AR a, int kcn) {
  if (!F32) return a.lo;
  if (kcn == 4 || kcn == 5) return a.lo;   // cos region: already bf16-packed
  union { uint4 u; float4 f; } l, h; l.u = a.lo; h.u = a.hi;
  uint4 o; o.x = pk2(l.f.x, l.f.y); o.y = pk2(l.f.z, l.f.w);
  o.z = pk2(h.f.x, h.f.y); o.w = pk2(h.f.z, h.f.w);
  return o;
}

// stage one 128x64 bf16 B-tile (16KB): 4 x global_load_lds(16B) per thread.
// Wave w writes ONLY its own quarter and later reads only that quarter.
__device__ __forceinline__ void b_issue(const bf16* __restrict__ wpk, int tile,
                                        bf16* BsBuf, int tid) {
  int w = tid >> 6;
  const bf16* g = wpk + (size_t)tile * 8192 + w * 2048 + (tid & 63) * 8;
  bf16* l = BsBuf + w * 2048;      // wave-uniform; HW adds lane*16B
#pragma unroll
  for (int i = 0; i < 4; ++i)
    gl_lds16(g + i * 512, l + i * 512);
}

template<bool F32>
__device__ __forceinline__ void gemm2_body(
    const void* mem, const void* lastup, const void* t, const void* feat,
    const int* __restrict__ src, const int* __restrict__ dst,
    const bf16* __restrict__ wpk,
    const void* bih, const void* bhh, const void* tw, const void* tb,
    const u64* __restrict__ key, const int* __restrict__ list,
    const u32* __restrict__ cnt, int use_list,
    void* out, int N, int E,
    char* smem, int* s_node, int* s_e, int* s_oth, int* s_act,
    float* s_dt, float* s_twb) {
  const int tid = threadIdx.x;
  const int bx = blockIdx.x;
  bf16 (*As)[BM2][72] = (bf16 (*)[BM2][72])smem;          //  9216 B (2 bufs)
  bf16* BsBase = (bf16*)(smem + 9216);                     // 32768 B (2 bufs)
  float (*Gs)[133] = (float (*)[133])smem;                 // overlay (epilogue)

  if (tid < BM2) {
    int r = tid, row = BM2 * bx + r, node = -1;
    if (use_list) { int c = (int)*cnt; if (row < c) node = list[row]; }
    else if (row < N) node = row;
    int act = 0, e = 0, oth = 0; float dtv = 0.f;
    if (node >= 0) {
      u32 b = (u32)key[node];
      if (b) {
        act = 1;
        int pos = (int)(b - 1u);
        if (pos < E) { e = pos; oth = dst[e]; } else { e = pos - E; oth = src[e]; }
        dtv = ldE<F32>(t, e) - ldE<F32>(lastup, node);
      }
    }
    if (node < 0) node = 0;
    s_node[r] = node; s_e[r] = e; s_oth[r] = oth; s_act[r] = act; s_dt[r] = dtv;
  }
  if (tid < 128) s_twb[tid] = ldE<F32>(tw, tid);
  else           s_twb[128 + (tid - 128)] = ldE<F32>(tb, tid - 128);
  __syncthreads();

  {  // stage A(kc=0); compiler waits for these loads at the pack
    AR a0 = a_fetch_raw<F32>(0, tid, mem, feat, s_node, s_e, s_oth, s_dt, s_twb);
    *(uint4*)&As[0][tid >> 3][(tid & 7) * 8] = a_pack<F32>(a0, 0);
  }
  __syncthreads();   // full drain once (prologue only)

  // B prologue: tiles 0,1 in flight (issued AFTER the drain)
  b_issue(wpk, 0, BsBase, tid);
  b_issue(wpk, 1, BsBase + 8192, tid);

  const int w = tid >> 6, l = tid & 63;
  const int mrow = l & 15, quad = l >> 4;
  f32x4 acc[4][2][2];   // [by][mi][ni]
#pragma unroll
  for (int by = 0; by < 4; ++by)
#pragma unroll
    for (int mi = 0; mi < 2; ++mi)
#pragma unroll
      for (int ni = 0; ni < 2; ++ni) acc[by][mi][ni] = (f32x4){0.f, 0.f, 0.f, 0.f};

  AR apre; apre.lo = (uint4){0,0,0,0}; apre.hi = apre.lo;
#pragma unroll 1
  for (int kc = 0; kc < 8; ++kc) {
    const int ka = kc & 1;
    short8 a[2][2];
#pragma unroll
    for (int by = 0; by < 4; ++by) {
      const int p = 4 * kc + by;
      // step1: A prefetch for next kc (1 load bf16 / 2 f32 / 0 cos)
      if (by == 0 && kc < 7)
        apre = a_fetch_raw<F32>(kc + 1, tid, mem, feat, s_node, s_e, s_oth, s_dt, s_twb);
      // step2: counted wait for B(p) (and transitively older A)
      if (by < 2) {
        if (kc == 3 || kc == 4 || kc == 7) { VMWAIT(4); }
        else if (F32)                      { VMWAIT(6); }
        else                               { VMWAIT(5); }
      } else if (by == 2)                  { VMWAIT(4); }
      else {
        if (kc == 7)                       { VMWAIT(0); }
        else                               { VMWAIT(4); }
      }
      // step3: register loads
      if (by == 0) {
#pragma unroll
        for (int ks2 = 0; ks2 < 2; ++ks2)
#pragma unroll
          for (int mi = 0; mi < 2; ++mi)
            a[ks2][mi] = *(const short8*)((const char*)&As[ka][0][0] +
                             (16 * mi + mrow) * 144 + ks2 * 64 + quad * 16);
      }
      const char* Bsb = (const char*)(BsBase + ((p & 1) << 13));
      short8 b[2][2];
#pragma unroll
      for (int ks2 = 0; ks2 < 2; ++ks2)
#pragma unroll
        for (int ni = 0; ni < 2; ++ni) {
          int j = 32 * w + 16 * ni + mrow;
          int off = (j * 128 + ks2 * 64 + quad * 16) ^ ((j & 7) << 4);
          b[ks2][ni] = *(const short8*)(Bsb + off);
        }
      // step4: MFMA (compiler inserts lgkmcnt for the ds_read deps)
      __builtin_amdgcn_s_setprio(1);
#pragma unroll
      for (int ks2 = 0; ks2 < 2; ++ks2)
#pragma unroll
        for (int mi = 0; mi < 2; ++mi)
#pragma unroll
          for (int ni = 0; ni < 2; ++ni)
            acc[by][mi][ni] = __builtin_amdgcn_mfma_f32_16x16x32_bf16(
                a[ks2][mi], b[ks2][ni], acc[by][mi][ni], 0, 0, 0);
      __builtin_amdgcn_s_setprio(0);
      // step5: refill the buffer just consumed (own reads retired via MFMA)
      if (p + 2 < 32)
        b_issue(wpk, p + 2, BsBase + ((p & 1) << 13), tid);
      // step6 (by3): As handoff -> the only cross-wave barrier
      if (by == 3) {
        if (kc < 7)
          *(uint4*)&As[ka ^ 1][tid >> 3][(tid & 7) * 8] = a_pack<F32>(apre, kc + 1);
        asm volatile("s_waitcnt lgkmcnt(0)" ::: "memory");
        __builtin_amdgcn_s_barrier();   // vmcnt NOT drained: B stays in flight
      }
    }
  }

  // ---- GRU epilogue per by (Gs overlays the dead As/Bs region) ----
#pragma unroll
  for (int by = 0; by < 4; ++by) {
#pragma unroll
    for (int mi = 0; mi < 2; ++mi)
#pragma unroll
      for (int ni = 0; ni < 2; ++ni)
#pragma unroll
        for (int reg = 0; reg < 4; ++reg)
          Gs[16 * mi + quad * 4 + reg][32 * w + 16 * ni + mrow] = acc[by][mi][ni][reg];
    __syncthreads();
    {
      int r = tid >> 3, giB = (tid & 7) * 4;
      if (s_act[r]) {
        int node = s_node[r];
#pragma unroll
        for (int q = 0; q < 4; ++q) {
          int gi = giB + q, gidx = 32 * by + gi;
          float rp  = Gs[r][gi]      + ldE<F32>(bih, gidx)       + ldE<F32>(bhh, gidx);
          float zp  = Gs[r][32 + gi] + ldE<F32>(bih, 128 + gidx) + ldE<F32>(bhh, 128 + gidx);
          float inp = Gs[r][64 + gi] + ldE<F32>(bih, 256 + gidx);
          float hnp = Gs[r][96 + gi] + ldE<F32>(bhh, 256 + gidx);
          float rg = 1.f / (1.f + expf(-rp));
          float zg = 1.f / (1.f + expf(-zp));
          float ng = tanhf(inp + rg * hnp);
          float h = ldE<F32>(mem, (size_t)node * D_ + gidx);
          stE<F32>(out, (size_t)node * D_ + gidx, (1.f - zg) * ng + zg * h);
        }
      }
    }
    __syncthreads();
  }
}

__global__ __launch_bounds__(256, 3)
void k_gemm2(const void* mem, const void* lastup, const void* t, const void* feat,
             const int* src, const int* dst, const bf16* wpk,
             const void* bih, const void* bhh, const void* tw, const void* tb,
             const u32* __restrict__ flag, const u64* __restrict__ key,
             const int* __restrict__ list, const u32* __restrict__ cnt, int use_list,
             void* out, int N, int E) {
  if (use_list && (int)*cnt <= BM2 * (int)blockIdx.x) return;  // uniform, pre-barrier
  __shared__ __align__(16) char smem[41984];   // As 9216 + Bs 2x16384; Gs overlay 17024
  __shared__ int s_node[BM2], s_e[BM2], s_oth[BM2], s_act[BM2];
  __shared__ float s_dt[BM2], s_twb[256];
  if (*flag)
    gemm2_body<true>(mem, lastup, t, feat, src, dst, wpk, bih, bhh, tw, tb,
                     key, list, cnt, use_list, out, N, E,
                     smem, s_node, s_e, s_oth, s_act, s_dt, s_twb);
  else
    gemm2_body<false>(mem, lastup, t, feat, src, dst, wpk, bih, bhh, tw, tb,
                      key, list, cnt, use_list, out, N, E,
                      smem, s_node, s_e, s_oth, s_act, s_dt, s_twb);
}

// ============================================================================
// FALLBACK (tiny ws): round-0 proven kernel, grid (mtiles,4), raw weights K=640.
// ============================================================================
template<bool F32>
__device__ __forceinline__ void gemm_body(
    const void* mem, const void* lastup, const void* t, const void* feat,
    const int* __restrict__ src, const int* __restrict__ dst,
    const void* wih, const void* whh, const void* bih, const void* bhh,
    const void* tw, const void* tb,
    const u64* __restrict__ key, const int* __restrict__ list,
    const u32* __restrict__ cnt, int use_list,
    void* out, int N, int E,
    bf16 (*As)[72], bf16 (*Bs)[72], float (*Gs)[132],
    int* s_node, int* s_e, int* s_oth, int* s_act, float* s_dt) {
  const int tid = threadIdx.x;
  const int bx = blockIdx.x, by = blockIdx.y;

  if (tid < BM) {
    int r = tid;
    int row = BM * bx + r;
    int node = -1;
    if (use_list) { int c = (int)*cnt; if (row < c) node = list[row]; }
    else if (row < N) node = row;
    int act = 0, e = 0, oth = 0; float dtv = 0.f;
    if (node >= 0) {
      u32 b = (u32)key[node];
      if (b) {
        act = 1;
        int pos = (int)(b - 1u);
        if (pos < E) { e = pos; oth = dst[e]; } else { e = pos - E; oth = src[e]; }
        dtv = ldE<F32>(t, e) - ldE<F32>(lastup, node);
      }
    }
    if (node < 0) node = 0;
    s_node[r] = node; s_e[r] = e; s_oth[r] = oth; s_act[r] = act; s_dt[r] = dtv;
  }

  const int w = tid >> 6, l = tid & 63;
  const int mrow = l & 15, quad = l >> 4;
  f32x4 acc[4][2];
#pragma unroll
  for (int mi = 0; mi < 4; ++mi)
#pragma unroll
    for (int ni = 0; ni < 2; ++ni) acc[mi][ni] = (f32x4){0.f, 0.f, 0.f, 0.f};

#pragma unroll 1
  for (int kc = 0; kc < KFB / BK; ++kc) {
    __syncthreads();
#pragma unroll
    for (int it = 0; it < 2; ++it) {
      int task = tid + 256 * it;
      int r = task >> 3, s = task & 7;
      int k0 = kc * BK + s * 8;
      bf16* dstp = &As[r][s * 8];
      if (k0 < 128)       stage8<F32>(mem,  (size_t)s_node[r] * D_ + k0, dstp);
      else if (k0 < 256)  stage8<F32>(mem,  (size_t)s_oth[r] * D_ + (k0 - 128), dstp);
      else if (k0 < 384) {
        float dtv = s_dt[r];
        float f[8];
#pragma unroll
        for (int q = 0; q < 8; ++q) {
          int j = k0 - 256 + q;
          f[q] = cosf(fmaf(dtv, ldE<F32>(tw, j), ldE<F32>(tb, j)));
        }
        uint4 o; o.x = pk2(f[0], f[1]); o.y = pk2(f[2], f[3]);
        o.z = pk2(f[4], f[5]); o.w = pk2(f[6], f[7]);
        *(uint4*)dstp = o;
      }
      else if (k0 < 512)  stage8<F32>(feat, (size_t)s_e[r] * D_ + (k0 - 384), dstp);
      else                stage8<F32>(mem,  (size_t)s_node[r] * D_ + (k0 - 512), dstp);
    }
#pragma unroll
    for (int it = 0; it < 4; ++it) {
      int task = tid + 256 * it;
      int j = task >> 3, s = task & 7;
      int k0 = kc * BK + s * 8;
      int grp = j >> 5, gi = j & 31;
      int gidx = 32 * by + gi;
      bf16* dstp = &Bs[j][s * 8];
      if (k0 < 512) {
        if (grp == 3) { *(uint4*)dstp = (uint4){0, 0, 0, 0}; }
        else {
          int srow = (grp == 0) ? gidx : (grp == 1) ? 128 + gidx : 256 + gidx;
          stage8<F32>(wih, (size_t)srow * 512 + k0, dstp);
        }
      } else {
        if (grp == 2) { *(uint4*)dstp = (uint4){0, 0, 0, 0}; }
        else {
          int srow = (grp == 0) ? gidx : (grp == 1) ? 128 + gidx : 256 + gidx;
          stage8<F32>(whh, (size_t)srow * D_ + (k0 - 512), dstp);
        }
      }
    }
    __syncthreads();
#pragma unroll
    for (int ks = 0; ks < BK; ks += 32) {
      short8 a[4], b[2];
#pragma unroll
      for (int mi = 0; mi < 4; ++mi)
        a[mi] = *(const short8*)&As[16 * mi + mrow][ks + quad * 8];
#pragma unroll
      for (int ni = 0; ni < 2; ++ni)
        b[ni] = *(const short8*)&Bs[32 * w + 16 * ni + mrow][ks + quad * 8];
#pragma unroll
      for (int mi = 0; mi < 4; ++mi)
#pragma unroll
        for (int ni = 0; ni < 2; ++ni)
          acc[mi][ni] = __builtin_amdgcn_mfma_f32_16x16x32_bf16(a[mi], b[ni], acc[mi][ni], 0, 0, 0);
    }
  }

#pragma unroll
  for (int mi = 0; mi < 4; ++mi)
#pragma unroll
    for (int ni = 0; ni < 2; ++ni)
#pragma unroll
      for (int reg = 0; reg < 4; ++reg)
        Gs[16 * mi + quad * 4 + reg][32 * w + 16 * ni + mrow] = acc[mi][ni][reg];
  __syncthreads();

  {
    int r = tid >> 2;
    int giB = (tid & 3) * 8;
    if (s_act[r]) {
      int node = s_node[r];
#pragma unroll
      for (int q = 0; q < 8; ++q) {
        int gi = giB + q;
        int gidx = 32 * by + gi;
        float rp  = Gs[r][gi]       + ldE<F32>(bih, gidx)       + ldE<F32>(bhh, gidx);
        float zp  = Gs[r][32 + gi]  + ldE<F32>(bih, 128 + gidx) + ldE<F32>(bhh, 128 + gidx);
        float inp = Gs[r][64 + gi]  + ldE<F32>(bih, 256 + gidx);
        float hnp = Gs[r][96 + gi]  + ldE<F32>(bhh, 256 + gidx);
        float rg = 1.f / (1.f + expf(-rp));
        float zg = 1.f / (1.f + expf(-zp));
        float ng = tanhf(inp + rg * hnp);
        float h = ldE<F32>(mem, (size_t)node * D_ + gidx);
        stE<F32>(out, (size_t)node * D_ + gidx, (1.f - zg) * ng + zg * h);
      }
    }
  }
}

__global__ __launch_bounds__(256)
void k_gemm_fb(const void* mem, const void* lastup, const void* t, const void* feat,
               const int* src, const int* dst,
               const void* wih, const void* whh, const void* bih, const void* bhh,
               const void* tw, const void* tb,
               const u32* __restrict__ flag, const u64* __restrict__ key,
               const int* __restrict__ list, const u32* __restrict__ cnt, int use_list,
               void* out, int N, int E) {
  if (use_list && (int)*cnt <= BM * (int)blockIdx.x) return;

  __shared__ __align__(16) bf16 As[BM][72];
  __shared__ __align__(16) bf16 Bs[BN][72];
  __shared__ __align__(16) float Gs[BM][132];
  __shared__ int s_node[BM], s_e[BM], s_oth[BM], s_act[BM];
  __shared__ float s_dt[BM];

  if (*flag)
    gemm_body<true>(mem, lastup, t, feat, src, dst, wih, whh, bih, bhh, tw, tb,
                    key, list, cnt, use_list, out, N, E,
                    As, Bs, Gs, s_node, s_e, s_oth, s_act, s_dt);
  else
    gemm_body<false>(mem, lastup, t, feat, src, dst, wih, whh, bih, bhh, tw, tb,
                     key, list, cnt, use_list, out, N, E,
                     As, Bs, Gs, s_node, s_e, s_oth, s_act, s_dt);
}

extern "C" void kernel_launch(void* const* d_in, const int* in_sizes, int n_in,
                              void* d_out, int out_size, void* d_ws, size_t ws_size,
                              hipStream_t stream) {
  const void* mem    = d_in[0];
  const void* lastup = d_in[1];
  const void* t      = d_in[2];
  const void* feat   = d_in[3];
  const void* tw     = d_in[4];
  const void* tb     = d_in[5];
  const void* wih    = d_in[6];
  const void* whh    = d_in[7];
  const void* bih    = d_in[8];
  const void* bhh    = d_in[9];
  const int*  src    = (const int*)d_in[10];
  const int*  dst    = (const int*)d_in[11];

  int N = in_sizes[0] / D_;
  int E = in_sizes[2];

  // ws: flag(16) + cnt(16) + key[N](8N) + list[N](4N, optional)
  //     + wpk (32 tiles x 8192 bf16 = 524288B, optional -> fallback kernel)
  char* ws = (char*)d_ws;
  size_t off = 0;
  u32* flag = (u32*)(ws + off); off += 16;
  u32* cnt  = (u32*)(ws + off); off += 16;
  u64* key  = (u64*)(ws + off); off += (size_t)N * 8;
  int* list = (int*)(ws + off); off += (size_t)N * 4;
  int use_list = (ws_size >= off) ? 1 : 0;
  bf16* wpk = (bf16*)(ws + off); off += (size_t)32 * 8192 * 2;
  int use2 = (ws_size >= off) ? 1 : 0;

  const int thr = 256;
  int nb = (N + thr - 1) / thr;
  int eb = (2 * E + thr - 1) / thr;

  k_preppack<<<dim3(nb), dim3(thr), 0, stream>>>(key, cnt, N, (const u32*)mem,
                                                 (const u32*)t, flag, wih, whh,
                                                 wpk, use2);
  k_scat<<<dim3(eb), dim3(thr), 0, stream>>>(src, dst, t, flag, key, E);
  k_compact<<<dim3(nb), dim3(thr), 0, stream>>>(mem, lastup, t, flag, key,
                                                list, cnt, use_list, d_out, N, E);
  if (use2) {
    int mt = (N + BM2 - 1) / BM2;
    k_gemm2<<<dim3(mt), dim3(thr), 0, stream>>>(
        mem, lastup, t, feat, src, dst, wpk, bih, bhh, tw, tb,
        flag, key, list, cnt, use_list, d_out, N, E);
  } else {
    int mt = (N + BM - 1) / BM;
    k_gemm_fb<<<dim3(mt, 4), dim3(thr), 0, stream>>>(
        mem, lastup, t, feat, src, dst, wih, whh, bih, bhh, tw, tb,
        flag, key, list, cnt, use_list, d_out, N, E);
  }
}